// Round 6
// baseline (662.079 us; speedup 1.0000x reference)
//
#include <hip/hip_runtime.h>
#include <math.h>

#define EPS 1e-6f

typedef float f32x2 __attribute__((ext_vector_type(2)));

__device__ __forceinline__ float bcast(float x, int srcLane) {
    return __int_as_float(__builtin_amdgcn_readlane(__float_as_int(x), srcLane));
}

// d = a*b + d element-wise via one packed-f32 fma. a: per-lane VGPR pair
// (pre-negated by caller when subtracting); b: uniform broadcast pair in an
// SGPR pair (single SGPR operand -> legal for one VALU instr).
__device__ __forceinline__ void pk_fma_vs(f32x2& d, f32x2 a, f32x2 b) {
    asm("v_pk_fma_f32 %0, %1, %2, %0" : "+v"(d) : "v"(a), "s"(b));
}

// Round 9: LDS now stores RATIO columns tt[j][k] = resid_j / bkk (rows
// k+1..63 only, diag excluded): 2016 floats + 1 dump slot = 2017/wave ->
// 32288 B/block <= 32768 -> 5 blocks/CU (20 waves, was 4/16). Subst reads tt
// directly (deletes per-step bcast+rcp+mul); epilogue's 1/L_mm kept in a
// register by lane k at step k (rsqf keeper). Instruction-neutral; payload
// is +25% occupancy to cover the per-step readlane->rsqrt->fma latency that
// 3 waves/SIMD left exposed (VALUBusy 80%).
constexpr int TRI = 2016;   // sum_k (63-k)
constexpr int WSLOT = TRI + 1;  // + dump slot

__global__ __launch_bounds__(256, 1) void vae_rec_kernel(const float* __restrict__ recon,
                                                         const float* __restrict__ orig,
                                                         float* __restrict__ out,
                                                         int npairs) {
    const int lane = threadIdx.x & 63;
    const int waveInBlock = threadIdx.x >> 6;
    const int pair = blockIdx.x * 4 + waveInBlock;

    __shared__ float lds[4 * WSLOT];
    float* wl = lds + waveInBlock * WSLOT;

    float kl = 0.0f;
    if (pair < npairs) {
        const float* Bm = recon + (size_t)pair * 4096;
        const float* Am = orig + (size_t)pair * 4096;

        float my_invm = 0.0f;  // lane m keeps 1/L_B[m][m] (set at step m)

        // ---- Phase 1: load B, Cholesky(B) residual recurrence, stage
        // ratio-columns tt to LDS ----
        float detB;
        {
            f32x2 rb2[32];
            const float4* pb = (const float4*)(Bm + lane * 64);
#pragma unroll
            for (int i = 0; i < 16; ++i) {
                float4 v = pb[i];
                rb2[2 * i].x = v.x; rb2[2 * i].y = v.y;
                rb2[2 * i + 1].x = v.z; rb2[2 * i + 1].y = v.w;
            }
            detB = 1.0f;
            int off = 0;  // constant-folded by full unroll
#pragma unroll
            for (int k = 0; k < 64; ++k) {
                float rbk = (k & 1) ? rb2[k >> 1].y : rb2[k >> 1].x;
                float bkk = bcast(rbk, k);  // residual diag (uniform)
                detB *= bkk;
                float rcpb = __builtin_amdgcn_rcpf(bkk);
                float tcol = rbk * rcpb;  // tt[lane][k], valid for lane > k
                // keeper: 1/L_B[k][k] = rsqrt(bkk) for the epilogue
                float rsq = __builtin_amdgcn_rsqf(bkk);
                if (lane == k) my_invm = rsq;
                // ratio-column write (rows k+1..63); others to the dump slot
                int idx = (lane > k) ? (off + lane - k - 1) : TRI;
                wl[idx] = tcol;
                if (k < 63) {
                    float nrk = -rbk;  // per-lane residual multiplier
                    f32x2 nrk2; nrk2.x = nrk; nrk2.y = nrk;
                    int j = k + 1;
                    if (j & 1) {  // odd first element: scalar on .y
                        float c = bcast(tcol, j);
                        rb2[j >> 1].y = __builtin_fmaf(nrk, c, rb2[j >> 1].y);
                        ++j;
                    }
#pragma unroll
                    for (int t = j >> 1; t < 32; ++t) {
                        f32x2 c;
                        c.x = bcast(tcol, 2 * t);
                        c.y = bcast(tcol, 2 * t + 1);
                        pk_fma_vs(rb2[t], nrk2, c);
                    }
                }
                off += 63 - k;
            }
        }  // rb2 dead here

        // ---- Phase 2: load A; fused Cholesky(A) + forward substitution ----
        f32x2 ra2[32];
        {
            const float4* pa = (const float4*)(Am + lane * 64);
#pragma unroll
            for (int i = 0; i < 16; ++i) {
                float4 v = pa[i];
                ra2[2 * i].x = v.x; ra2[2 * i].y = v.y;
                ra2[2 * i + 1].x = v.z; ra2[2 * i + 1].y = v.w;
            }
        }
        float detA = 1.0f;
        int off = 0;
#pragma unroll
        for (int k = 0; k < 64; ++k) {
            // Cholesky(A) step k (readlane broadcasts, unchanged)
            float rak = (k & 1) ? ra2[k >> 1].y : ra2[k >> 1].x;
            float akk = bcast(rak, k);
            detA *= akk;
            float ia = __builtin_amdgcn_rsqf(akk);
            rak *= ia;  // finalize column k of L_A (lanes >= k)
            if (k & 1) ra2[k >> 1].y = rak; else ra2[k >> 1].x = rak;
            if (k < 63) {
                float nlka = -rak;
                f32x2 nlka2; nlka2.x = nlka; nlka2.y = nlka;
                int j = k + 1;
                if (j & 1) {
                    float c = bcast(rak, j);
                    ra2[j >> 1].y = __builtin_fmaf(nlka, c, ra2[j >> 1].y);
                    ++j;
                }
#pragma unroll
                for (int t = j >> 1; t < 32; ++t) {
                    f32x2 c;
                    c.x = bcast(rak, 2 * t);
                    c.y = bcast(rak, 2 * t + 1);
                    pk_fma_vs(ra2[t], nlka2, c);
                }
            }
            // Substitution step k: tt read directly from the ratio-column.
            int idx = off + ((lane > k) ? (lane - k - 1) : 0);
            float tval = wl[idx];
            // freeze: lanes <= k stop updating -> their row regs keep their
            // own row's unscaled W values; fro recovered in the epilogue.
            float tt = (lane > k) ? tval : 0.0f;
            float ntt = -tt;
            f32x2 ntt2; ntt2.x = ntt; ntt2.y = ntt;
#pragma unroll
            for (int t = 0; t < ((k + 1) >> 1); ++t) {  // pairs c2 = 2t, 2t+1
                f32x2 u;
                u.x = bcast(ra2[t].x, k);  // frozen row k (uniform)
                u.y = bcast(ra2[t].y, k);
                pk_fma_vs(ra2[t], ntt2, u);  // update rows > k
            }
            if (!(k & 1)) {  // scalar tail c2 = k (k even -> component .x)
                float u = bcast(ra2[k >> 1].x, k);
                ra2[k >> 1].x = __builtin_fmaf(ntt, u, ra2[k >> 1].x);
            }
            off += 63 - k;
        }

        // Epilogue: row `lane` of W (unscaled) sits frozen in rA[0..lane];
        // scale by the kept 1/L_B[lane][lane].
        float invm = my_invm;
        float fr = 0.0f;
#pragma unroll
        for (int c = 0; c < 64; ++c) {
            float rv = (c & 1) ? ra2[c >> 1].y : ra2[c >> 1].x;
            float v = (c <= lane) ? rv : 0.0f;  // c>lane regs hold non-W data
            fr = __builtin_fmaf(v, v, fr);
        }
        fr = fr * invm * invm;
#pragma unroll
        for (int s = 1; s < 64; s <<= 1) fr += __shfl_xor(fr, s, 64);

        float sdetB = __builtin_sqrtf(detB);
        float sdetA = __builtin_sqrtf(detA);
        float logdet = __builtin_logf((sdetA + EPS) / (sdetB + EPS));
        kl = 0.5f * (fr - 64.0f + logdet);
    }

    __shared__ float sred[4];
    if (lane == 0) sred[waveInBlock] = kl;
    __syncthreads();
    if (threadIdx.x == 0) {
        float s = sred[0] + sred[1] + sred[2] + sred[3];
        atomicAdd(out + 1, -s);
    }
}

// Encoded: 32x32 Cholesky (sqrt-det) + trace. Two matrices per wave (lanes
// 0-31 / 32-63); broadcasts via two static readlanes + select on the half.
// (unchanged: ~35 us standalone)
__global__ __launch_bounds__(256, 1) void vae_enc_kernel(const float* __restrict__ enc,
                                                         float* __restrict__ out,
                                                         int nmats) {
    const int lane = threadIdx.x & 63;
    const int r = lane & 31;
    const bool hi = lane >= 32;
    const int wv = (int)(blockIdx.x * 4 + (threadIdx.x >> 6));
    const int mat = wv * 2 + (hi ? 1 : 0);

    float kl = 0.0f;
    if (mat < nmats) {
        const float* M = enc + (size_t)mat * 1024;
        float rm[32];
        {
            const float4* pm = (const float4*)(M + r * 32);
#pragma unroll
            for (int i = 0; i < 8; ++i) {
                float4 v = pm[i];
                rm[4 * i + 0] = v.x; rm[4 * i + 1] = v.y;
                rm[4 * i + 2] = v.z; rm[4 * i + 3] = v.w;
            }
        }

        float tr = 0.0f;
#pragma unroll
        for (int i = 0; i < 32; ++i)
            if (i == r) tr = rm[i];
#pragma unroll
        for (int m = 1; m < 32; m <<= 1)
            tr += __shfl_xor(tr, m, 64);

        float det = 1.0f;
#pragma unroll
        for (int k = 0; k < 32; ++k) {
            float a0 = bcast(rm[k], k);
            float a1 = bcast(rm[k], k + 32);
            float akk = hi ? a1 : a0;
            det *= akk;
            float inv = __builtin_amdgcn_rsqf(akk);
            rm[k] *= inv;
#pragma unroll
            for (int j = k + 1; j < 32; ++j) {
                float l0 = bcast(rm[k], j);
                float l1 = bcast(rm[k], j + 32);
                float ljk = hi ? l1 : l0;
                rm[j] = __builtin_fmaf(-rm[k], ljk, rm[j]);
            }
        }

        float sdet = __builtin_sqrtf(det);
        float logdet = __builtin_logf((sdet + EPS) / (1.0f + EPS));
        kl = 0.5f * (tr - 32.0f + logdet);
    }

    __shared__ float sred[8];
    if (r == 0) sred[threadIdx.x >> 5] = kl;
    __syncthreads();
    if (threadIdx.x == 0) {
        float s = 0.0f;
#pragma unroll
        for (int i = 0; i < 8; ++i) s += sred[i];
        atomicAdd(out + 2, -s);
    }
}

__global__ void vae_init_kernel(float* __restrict__ out) {
    if (threadIdx.x < 3) out[threadIdx.x] = 0.0f;
}

__global__ void vae_final_kernel(float* __restrict__ out) {
    if (threadIdx.x == 0) out[0] = out[1] + out[2];
}

extern "C" void kernel_launch(void* const* d_in, const int* in_sizes, int n_in,
                              void* d_out, int out_size, void* d_ws, size_t ws_size,
                              hipStream_t stream) {
    const float* recon = (const float*)d_in[0];
    const float* orig = (const float*)d_in[1];
    const float* enc = (const float*)d_in[2];
    float* out = (float*)d_out;

    const int npairs = in_sizes[0] / 4096;   // 8192
    const int nmats = in_sizes[2] / 1024;    // 8192

    vae_init_kernel<<<1, 64, 0, stream>>>(out);

    const int rec_blocks = (npairs + 3) / 4;          // 4 waves/block, 1 pair/wave
    vae_rec_kernel<<<rec_blocks, 256, 0, stream>>>(recon, orig, out, npairs);

    const int enc_blocks = (nmats + 7) / 8;           // 8 matrices/block (2 per wave)
    vae_enc_kernel<<<enc_blocks, 256, 0, stream>>>(enc, out, nmats);

    vae_final_kernel<<<1, 64, 0, stream>>>(out);
}

// Round 7
// 400.560 us; speedup vs baseline: 1.6529x; 1.6529x over previous
//
#include <hip/hip_runtime.h>
#include <math.h>

#define EPS 1e-6f

typedef float f32x2 __attribute__((ext_vector_type(2)));

__device__ __forceinline__ float bcast(float x, int srcLane) {
    return __int_as_float(__builtin_amdgcn_readlane(__float_as_int(x), srcLane));
}

// d = a*b + d element-wise via one packed-f32 fma. a: per-lane VGPR pair
// (pre-negated by caller when subtracting); b: uniform broadcast pair in an
// SGPR pair (single SGPR operand -> legal for one VALU instr).
__device__ __forceinline__ void pk_fma_vs(f32x2& d, f32x2 a, f32x2 b) {
    asm("v_pk_fma_f32 %0, %1, %2, %0" : "+v"(d) : "v"(a), "s"(b));
}

// Packed lower-triangular storage for L_B in LDS: column k (rows k..63) at
// offset off(k) = k*(129-k)/2; 2080 floats + 64 dump slots.
constexpr int TRI = 2080;
constexpr int WSLOT = TRI + 64;  // 8576 B per wave

// Round 10: rec reverted to the round-8 kernel EXACTLY (verified 191 us,
// VALUBusy 80%). Round 9's ratio-column/5-blocks config kept VALU work
// identical (busy-product 151 vs 153 us) but doubled wall time -- higher
// occupancy did not cover the per-step LDS-sourced critical path; in-register
// broadcasts are the winning family. Do not touch this kernel's LDS layout
// or occupancy again.
__global__ __launch_bounds__(256, 1) void vae_rec_kernel(const float* __restrict__ recon,
                                                         const float* __restrict__ orig,
                                                         float* __restrict__ out,
                                                         int npairs) {
    const int lane = threadIdx.x & 63;
    const int waveInBlock = threadIdx.x >> 6;
    const int pair = blockIdx.x * 4 + waveInBlock;

    __shared__ float lds[4 * WSLOT];
    float* wl = lds + waveInBlock * WSLOT;

    float kl = 0.0f;
    if (pair < npairs) {
        const float* Bm = recon + (size_t)pair * 4096;
        const float* Am = orig + (size_t)pair * 4096;

        // ---- Phase 1: load B, Cholesky(B), stage columns to LDS ----
        float detB;
        {
            f32x2 rb2[32];
            const float4* pb = (const float4*)(Bm + lane * 64);
#pragma unroll
            for (int i = 0; i < 16; ++i) {
                float4 v = pb[i];
                rb2[2 * i].x = v.x; rb2[2 * i].y = v.y;
                rb2[2 * i + 1].x = v.z; rb2[2 * i + 1].y = v.w;
            }
            detB = 1.0f;
            int off = 0;  // constant-folded by full unroll
#pragma unroll
            for (int k = 0; k < 64; ++k) {
                float rbk = (k & 1) ? rb2[k >> 1].y : rb2[k >> 1].x;
                float bkk = bcast(rbk, k);
                detB *= bkk;
                float ib = __builtin_amdgcn_rsqf(bkk);
                float lk = rbk * ib;  // L_B[lane][k], valid for lane >= k
                // packed column write; lanes < k go to the dump region
                int idx = (lane >= k) ? (off + lane - k) : (TRI + lane);
                wl[idx] = lk;
                off += 64 - k;
                if (k < 63) {
                    float nlk = -lk;
                    f32x2 nlk2; nlk2.x = nlk; nlk2.y = nlk;
                    int j = k + 1;
                    if (j & 1) {  // odd first element: scalar on .y
                        float c = bcast(lk, j);
                        rb2[j >> 1].y = __builtin_fmaf(nlk, c, rb2[j >> 1].y);
                        ++j;
                    }
#pragma unroll
                    for (int t = j >> 1; t < 32; ++t) {
                        f32x2 c;
                        c.x = bcast(lk, 2 * t);
                        c.y = bcast(lk, 2 * t + 1);
                        pk_fma_vs(rb2[t], nlk2, c);
                    }
                }
            }
        }  // rb2 dead here

        // ---- Phase 2: load A; fused Cholesky(A) + forward substitution ----
        f32x2 ra2[32];
        {
            const float4* pa = (const float4*)(Am + lane * 64);
#pragma unroll
            for (int i = 0; i < 16; ++i) {
                float4 v = pa[i];
                ra2[2 * i].x = v.x; ra2[2 * i].y = v.y;
                ra2[2 * i + 1].x = v.z; ra2[2 * i + 1].y = v.w;
            }
        }
        float detA = 1.0f;
        int off = 0;
#pragma unroll
        for (int k = 0; k < 64; ++k) {
            // Cholesky(A) step k
            float rak = (k & 1) ? ra2[k >> 1].y : ra2[k >> 1].x;
            float akk = bcast(rak, k);
            detA *= akk;
            float ia = __builtin_amdgcn_rsqf(akk);
            rak *= ia;  // finalize column k of L_A (lanes >= k)
            if (k & 1) ra2[k >> 1].y = rak; else ra2[k >> 1].x = rak;
            if (k < 63) {
                float nlka = -rak;
                f32x2 nlka2; nlka2.x = nlka; nlka2.y = nlka;
                int j = k + 1;
                if (j & 1) {
                    float c = bcast(rak, j);
                    ra2[j >> 1].y = __builtin_fmaf(nlka, c, ra2[j >> 1].y);
                    ++j;
                }
#pragma unroll
                for (int t = j >> 1; t < 32; ++t) {
                    f32x2 c;
                    c.x = bcast(rak, 2 * t);
                    c.y = bcast(rak, 2 * t + 1);
                    pk_fma_vs(ra2[t], nlka2, c);
                }
            }
            // Substitution step k: row k of W = L_B^{-1} L_A.
            int idx = off + ((lane >= k) ? (lane - k) : 0);  // sub-k lanes: broadcast read
            float cB = wl[idx];                               // L_B[lane][k]
            off += 64 - k;
            float bii = bcast(cB, k);
            float inv = __builtin_amdgcn_rcpf(bii);
            // freeze: lanes <= k stop updating -> their row regs keep their
            // own row's unscaled W values; fro recovered in the epilogue.
            float tt = (lane > k) ? (cB * inv) : 0.0f;
            float ntt = -tt;
            f32x2 ntt2; ntt2.x = ntt; ntt2.y = ntt;
#pragma unroll
            for (int t = 0; t < ((k + 1) >> 1); ++t) {  // pairs c2 = 2t, 2t+1
                f32x2 u;
                u.x = bcast(ra2[t].x, k);  // frozen row k (uniform)
                u.y = bcast(ra2[t].y, k);
                pk_fma_vs(ra2[t], ntt2, u);  // update rows > k
            }
            if (!(k & 1)) {  // scalar tail c2 = k (k even -> component .x)
                float u = bcast(ra2[k >> 1].x, k);
                ra2[k >> 1].x = __builtin_fmaf(ntt, u, ra2[k >> 1].x);
            }
        }

        // Epilogue: row `lane` of W (unscaled) sits frozen in rA[0..lane];
        // scale by rcp(L_B[lane][lane]) read from packed column start.
        const int m = lane;
        const int offm = (m * (129 - m)) >> 1;
        float dm = wl[offm];
        float invm = __builtin_amdgcn_rcpf(dm);
        float fr = 0.0f;
#pragma unroll
        for (int c = 0; c < 64; ++c) {
            float rv = (c & 1) ? ra2[c >> 1].y : ra2[c >> 1].x;
            float v = (c <= lane) ? rv : 0.0f;  // c>lane regs hold non-W data
            fr = __builtin_fmaf(v, v, fr);
        }
        fr = fr * invm * invm;
#pragma unroll
        for (int s = 1; s < 64; s <<= 1) fr += __shfl_xor(fr, s, 64);

        float sdetB = __builtin_sqrtf(detB);
        float sdetA = __builtin_sqrtf(detA);
        float logdet = __builtin_logf((sdetA + EPS) / (sdetB + EPS));
        kl = 0.5f * (fr - 64.0f + logdet);
    }

    __shared__ float sred[4];
    if (lane == 0) sred[waveInBlock] = kl;
    __syncthreads();
    if (threadIdx.x == 0) {
        float s = sred[0] + sred[1] + sred[2] + sred[3];
        atomicAdd(out + 1, -s);
    }
}

// Encoded: 32x32 Cholesky (sqrt-det) + trace. Two matrices per wave (lanes
// 0-31 / 32-63). Round 10: j-loop broadcast via ds_bpermute (crosslane on
// the LDS pipe, reads other lanes' REGISTERS -- no LDS memory round trip):
// dst_i = src[vb/4 + j] where vb=(lane&32)<<2 selects the half. Replaces
// 2 readlanes + cndmask + fma (4 VALU/elem) with 1 bpermute (DS) + 1 fma
// (1 VALU/elem). Diagonal path keeps readlanes (serial latency chain).
// This is also the A/B probe for porting bpermute into rec's hot loops.
__global__ __launch_bounds__(256, 1) void vae_enc_kernel(const float* __restrict__ enc,
                                                         float* __restrict__ out,
                                                         int nmats) {
    const int lane = threadIdx.x & 63;
    const int r = lane & 31;
    const bool hi = lane >= 32;
    const int wv = (int)(blockIdx.x * 4 + (threadIdx.x >> 6));
    const int mat = wv * 2 + (hi ? 1 : 0);
    const int vb = (lane & 32) << 2;  // byte base: 0 (lo half) / 128 (hi half)

    float kl = 0.0f;
    if (mat < nmats) {
        const float* M = enc + (size_t)mat * 1024;
        float rm[32];
        {
            const float4* pm = (const float4*)(M + r * 32);
#pragma unroll
            for (int i = 0; i < 8; ++i) {
                float4 v = pm[i];
                rm[4 * i + 0] = v.x; rm[4 * i + 1] = v.y;
                rm[4 * i + 2] = v.z; rm[4 * i + 3] = v.w;
            }
        }

        float tr = 0.0f;
#pragma unroll
        for (int i = 0; i < 32; ++i)
            if (i == r) tr = rm[i];
#pragma unroll
        for (int m = 1; m < 32; m <<= 1)
            tr += __shfl_xor(tr, m, 64);

        float det = 1.0f;
#pragma unroll
        for (int k = 0; k < 32; ++k) {
            float a0 = bcast(rm[k], k);
            float a1 = bcast(rm[k], k + 32);
            float akk = hi ? a1 : a0;
            det *= akk;
            float inv = __builtin_amdgcn_rsqf(akk);
            rm[k] *= inv;
            float nl = -rm[k];
#pragma unroll
            for (int j = k + 1; j < 32; ++j) {
                // per-half broadcast of L[j][k]: lane (half*32 + j)'s rm[k]
                int p = __builtin_amdgcn_ds_bpermute(vb + 4 * j, __float_as_int(rm[k]));
                rm[j] = __builtin_fmaf(nl, __int_as_float(p), rm[j]);
            }
        }

        float sdet = __builtin_sqrtf(det);
        float logdet = __builtin_logf((sdet + EPS) / (1.0f + EPS));
        kl = 0.5f * (tr - 32.0f + logdet);
    }

    __shared__ float sred[8];
    if (r == 0) sred[threadIdx.x >> 5] = kl;
    __syncthreads();
    if (threadIdx.x == 0) {
        float s = 0.0f;
#pragma unroll
        for (int i = 0; i < 8; ++i) s += sred[i];
        atomicAdd(out + 2, -s);
    }
}

__global__ void vae_init_kernel(float* __restrict__ out) {
    if (threadIdx.x < 3) out[threadIdx.x] = 0.0f;
}

__global__ void vae_final_kernel(float* __restrict__ out) {
    if (threadIdx.x == 0) out[0] = out[1] + out[2];
}

extern "C" void kernel_launch(void* const* d_in, const int* in_sizes, int n_in,
                              void* d_out, int out_size, void* d_ws, size_t ws_size,
                              hipStream_t stream) {
    const float* recon = (const float*)d_in[0];
    const float* orig = (const float*)d_in[1];
    const float* enc = (const float*)d_in[2];
    float* out = (float*)d_out;

    const int npairs = in_sizes[0] / 4096;   // 8192
    const int nmats = in_sizes[2] / 1024;    // 8192

    vae_init_kernel<<<1, 64, 0, stream>>>(out);

    const int rec_blocks = (npairs + 3) / 4;          // 4 waves/block, 1 pair/wave
    vae_rec_kernel<<<rec_blocks, 256, 0, stream>>>(recon, orig, out, npairs);

    const int enc_blocks = (nmats + 7) / 8;           // 8 matrices/block (2 per wave)
    vae_enc_kernel<<<enc_blocks, 256, 0, stream>>>(enc, out, nmats);

    vae_final_kernel<<<1, 64, 0, stream>>>(out);
}